// Round 7
// baseline (202.133 us; speedup 1.0000x reference)
//
#include <hip/hip_runtime.h>

// DCT_18769007084406: RGB->YCbCr (1x1 conv) -> 8x8 stride-8 block DCT
// (grouped conv) -> 32x repeated (t-min)/d normalization (closed form).
//
// R9: fuse all 3 channels into one wave -- kill the 3x read redundancy.
// R5-R8 (1 wave = 1 channel) were pinned at 59-62us regardless of MLP
// structure (6 or 24 loads in flight, 25-33% occupancy): the invariant was
// 402MB of LOGICAL vector-memory traffic (3x re-read of R/G/B: each
// channel-wave loaded all three planes and used one) moving at ~6.8TB/s
// aggregate = ~10-11 B/cy/CU, the per-CU vmem path ceiling (m13). L3
// absorbed the redundancy at HBM (FETCH 74MB) but the CUs paid per byte.
// Now wave-task = (band, column-half): each lane loads its 4 rows of
// R,G,B once (24 float4s) and computes Y,Cb,Cr from the same registers.
// Logical traffic 402->201MB; total VALU unchanged (3x per wave, 1/3
// waves). Per-row compute (~456 VALU ops) covers next-row load latency,
// so plain compiler-scheduled loads suffice (R8's asm burst proved
// no-gain). acc[3][4][8]=96 VGPR, all-static indices; launch_bounds
// (128,3) caps ~170 VGPR -> 3 waves/SIMD.

#define HW 512
#define CHST (HW * HW)       // channel stride in x
#define NPAIR 6144           // 32 * 192 (b, out-channel) pairs
#define EPS 1e-6f

// basis[u][i] = c(u) * cos(pi*u*(i+0.5)/8); c(0)=sqrt(1/8), c(u>0)=0.5
static constexpr float BASIS[8][8] = {
  { 0.35355339059327373f, 0.35355339059327373f, 0.35355339059327373f, 0.35355339059327373f,
    0.35355339059327373f, 0.35355339059327373f, 0.35355339059327373f, 0.35355339059327373f },
  { 0.49039264020161522f, 0.41573480615127262f, 0.27778511650980114f, 0.09754516100806412f,
   -0.09754516100806412f,-0.27778511650980114f,-0.41573480615127262f,-0.49039264020161522f },
  { 0.46193976625564337f, 0.19134171618254492f,-0.19134171618254492f,-0.46193976625564337f,
   -0.46193976625564337f,-0.19134171618254492f, 0.19134171618254492f, 0.46193976625564337f },
  { 0.41573480615127262f,-0.09754516100806412f,-0.49039264020161522f,-0.27778511650980114f,
    0.27778511650980114f, 0.49039264020161522f, 0.09754516100806412f,-0.41573480615127262f },
  { 0.35355339059327373f,-0.35355339059327373f,-0.35355339059327373f, 0.35355339059327373f,
    0.35355339059327373f,-0.35355339059327373f,-0.35355339059327373f, 0.35355339059327373f },
  { 0.27778511650980114f,-0.49039264020161522f, 0.09754516100806412f, 0.41573480615127262f,
   -0.41573480615127262f,-0.09754516100806412f, 0.49039264020161522f,-0.27778511650980114f },
  { 0.19134171618254492f,-0.46193976625564337f, 0.46193976625564337f,-0.19134171618254492f,
   -0.19134171618254492f, 0.46193976625564337f,-0.46193976625564337f, 0.19134171618254492f },
  { 0.09754516100806412f,-0.27778511650980114f, 0.41573480615127262f,-0.49039264020161522f,
    0.49039264020161522f,-0.41573480615127262f, 0.27778511650980114f,-0.09754516100806412f }
};

// t_32 = a^32 * t0 - min * sum_{k=1..32} a^k, a = 1/(max-min+eps)
__global__ void precomp_norm(const float* __restrict__ max_,
                             const float* __restrict__ min_,
                             float* __restrict__ so) {
    int i = blockIdx.x * 256 + threadIdx.x;
    if (i >= NPAIR) return;
    float mn = min_[i], mx = max_[i];
    float d = mx - mn + EPS;
    float a = 1.0f / d;
    float a2 = a * a, a4 = a2 * a2, a8 = a4 * a4, a16 = a8 * a8, a32 = a16 * a16;
    float geo = a * (1.0f - a32) / (1.0f - a);   // sum_{k=1..32} a^k
    so[2 * i]     = a32;
    so[2 * i + 1] = -mn * geo;
}

template <bool USE_WS>
__global__ __launch_bounds__(128, 3)
void dct_kernel(const float* __restrict__ x,
                const float* __restrict__ ycbcr_w,
                const float* __restrict__ so,
                const float* __restrict__ max_,
                const float* __restrict__ min_,
                float* __restrict__ out) {
    // block = band (b*64+by); wave = column-half; 2048 blocks x 2 waves.
    const int band = blockIdx.x;
    const int half = threadIdx.x >> 6;
    const int lane = threadIdx.x & 63;
    const int rh   = lane >> 5;            // row-half: rows rh*4 .. rh*4+3
    const int lx   = lane & 31;            // block-col within the half

    const int by   = band & 63;
    const int b    = band >> 6;
    const int bx   = half * 32 + lx;       // this lane's 8x8 block column

    // all 9 channel weights (wave-uniform scalars)
    float w[9];
#pragma unroll
    for (int i = 0; i < 9; ++i) w[i] = ycbcr_w[i];

    // lane's 4 rows start here
    const float* base = x + (size_t)(b * 3) * CHST
                          + (size_t)(by * 8 + rh * 4) * HW + bx * 8;

    float acc[3][4][8];   // acc[c][u0][v] for u = rh*4 + u0
#pragma unroll
    for (int c = 0; c < 3; ++c)
#pragma unroll
        for (int u0 = 0; u0 < 4; ++u0)
#pragma unroll
            for (int v = 0; v < 8; ++v) acc[c][u0][v] = 0.0f;

#pragma unroll
    for (int t = 0; t < 4; ++t) {
        const float* rp = base + t * HW;
        // lane bx reads 32B at bx*32 -> wave covers a contiguous 2KB row
        float4 Ra = *(const float4*)(rp);
        float4 Rb = *(const float4*)(rp + 4);
        float4 Ga = *(const float4*)(rp + CHST);
        float4 Gb = *(const float4*)(rp + CHST + 4);
        float4 Ba = *(const float4*)(rp + 2 * CHST);
        float4 Bb = *(const float4*)(rp + 2 * CHST + 4);

        float R[8] = {Ra.x, Ra.y, Ra.z, Ra.w, Rb.x, Rb.y, Rb.z, Rb.w};
        float G[8] = {Ga.x, Ga.y, Ga.z, Ga.w, Gb.x, Gb.y, Gb.z, Gb.w};
        float B[8] = {Ba.x, Ba.y, Ba.z, Ba.w, Bb.x, Bb.y, Bb.z, Bb.w};

        // All three channels from the same loaded registers.
#pragma unroll
        for (int c = 0; c < 3; ++c) {
            const float wr = w[3 * c], wg = w[3 * c + 1], wb = w[3 * c + 2];
            float y[8];
#pragma unroll
            for (int j = 0; j < 8; ++j)
                y[j] = fmaf(wr, R[j], fmaf(wg, G[j], wb * B[j]));

            // row DCT: z[v] = sum_j basis[v][j] * y[j]
            float z[8];
#pragma unroll
            for (int v = 0; v < 8; ++v) {
                float zz = y[0] * BASIS[v][0];
#pragma unroll
                for (int j = 1; j < 8; ++j)
                    zz = fmaf(y[j], BASIS[v][j], zz);
                z[v] = zz;
            }

            // partner row-half's z for the same block (lane ^ 32)
            float pz[8];
#pragma unroll
            for (int v = 0; v < 8; ++v)
                pz[v] = __shfl_xor(z[v], 32, 64);

            // own row gi = rh*4+t, partner row (1-rh)*4+t.
            // Compile-time indices, runtime rh -> cndmask between literals.
#pragma unroll
            for (int u0 = 0; u0 < 4; ++u0) {
                const float bo = rh ? BASIS[4 + u0][4 + t] : BASIS[u0][t];
                const float bp = rh ? BASIS[4 + u0][t]     : BASIS[u0][4 + t];
#pragma unroll
                for (int v = 0; v < 8; ++v)
                    acc[c][u0][v] = fmaf(bo, z[v], fmaf(bp, pz[v], acc[c][u0][v]));
            }
        }
    }

    const int uh = rh * 4;                 // lane stores its u-half
#pragma unroll
    for (int c = 0; c < 3; ++c) {
        const int obase = b * 192 + c * 64;      // first output channel index
        float* op = out + ((size_t)obase * 64 + by) * 64 + bx;
        const float2* sop = (const float2*)so + obase;   // (scale, offset)

#pragma unroll
        for (int u0 = 0; u0 < 4; ++u0) {
#pragma unroll
            for (int v = 0; v < 8; ++v) {
                const int k = (uh + u0) * 8 + v;
                float s, o;
                if (USE_WS) {
                    float2 p = sop[k];           // scalar-uniform table
                    s = p.x;
                    o = p.y;
                } else {
                    float mn = min_[obase + k], mx = max_[obase + k];
                    float d  = mx - mn + EPS;
                    float a  = 1.0f / d;
                    float a2 = a * a, a4 = a2 * a2, a8 = a4 * a4, a16 = a8 * a8, a32 = a16 * a16;
                    s = a32;
                    o = -mn * (a * (1.0f - a32) / (1.0f - a));
                }
                op[(size_t)k * 4096] = fmaf(s, acc[c][u0][v], o);
            }
        }
    }
}

extern "C" void kernel_launch(void* const* d_in, const int* in_sizes, int n_in,
                              void* d_out, int out_size, void* d_ws, size_t ws_size,
                              hipStream_t stream) {
    const float* x    = (const float*)d_in[0];
    const float* max_ = (const float*)d_in[1];
    const float* min_ = (const float*)d_in[2];
    const float* yw   = (const float*)d_in[3];
    float* out = (float*)d_out;
    float* so  = (float*)d_ws;

    const bool use_ws = (ws_size >= (size_t)NPAIR * 2 * sizeof(float));
    // 2048 bands, one band per 128-thread block (2 waves = 2 column halves)
    if (use_ws) {
        precomp_norm<<<(NPAIR + 255) / 256, 256, 0, stream>>>(max_, min_, so);
        dct_kernel<true><<<2048, 128, 0, stream>>>(x, yw, so, max_, min_, out);
    } else {
        dct_kernel<false><<<2048, 128, 0, stream>>>(x, yw, nullptr, max_, min_, out);
    }
}

// Round 8
// 193.492 us; speedup vs baseline: 1.0447x; 1.0447x over previous
//
#include <hip/hip_runtime.h>

// DCT_18769007084406: RGB->YCbCr (1x1 conv) -> 8x8 stride-8 block DCT
// (grouped conv) -> 32x repeated (t-min)/d normalization (closed form).
//
// R10: band-block co-location. Evidence so far: R4 (704MB logical vmem)
// = 95us, R5-R8 (402MB logical) = 59-62us regardless of MLP structure ->
// both sit at ~7TB/s LOGICAL vector-memory rate; FETCH(HBM) is only 74MB,
// so the 3x channel re-read is served by L3 at ~7TB/s effective -- the
// wall. R9 fused channels into one wave (201MB logical) but acc[96]
// spilled (~20 floats/lane -> WRITE_SIZE +20MB exactly) and regressed.
// Fix the sharing WITHOUT register pressure: keep R5's per-wave kernel
// verbatim (32 acc, rh row-split, shfl_xor cross-half combine, ~64 VGPR,
// compiler-scheduled loads -- R8 proved asm-burst MLP adds nothing), but
// put all 6 wave-tasks of one band (3 channels x 2 column-halves) in ONE
// 384-thread block. The 3 channel-waves of a half-band now run on the
// SAME CU and issue identical cache-line loads within a small skew ->
// L1/MSHR dedup; redundant reads never reach L3. Logical redundancy ~free.

#define HW 512
#define CHST (HW * HW)       // channel stride in x
#define NPAIR 6144           // 32 * 192 (b, out-channel) pairs
#define EPS 1e-6f

// basis[u][i] = c(u) * cos(pi*u*(i+0.5)/8); c(0)=sqrt(1/8), c(u>0)=0.5
static constexpr float BASIS[8][8] = {
  { 0.35355339059327373f, 0.35355339059327373f, 0.35355339059327373f, 0.35355339059327373f,
    0.35355339059327373f, 0.35355339059327373f, 0.35355339059327373f, 0.35355339059327373f },
  { 0.49039264020161522f, 0.41573480615127262f, 0.27778511650980114f, 0.09754516100806412f,
   -0.09754516100806412f,-0.27778511650980114f,-0.41573480615127262f,-0.49039264020161522f },
  { 0.46193976625564337f, 0.19134171618254492f,-0.19134171618254492f,-0.46193976625564337f,
   -0.46193976625564337f,-0.19134171618254492f, 0.19134171618254492f, 0.46193976625564337f },
  { 0.41573480615127262f,-0.09754516100806412f,-0.49039264020161522f,-0.27778511650980114f,
    0.27778511650980114f, 0.49039264020161522f, 0.09754516100806412f,-0.41573480615127262f },
  { 0.35355339059327373f,-0.35355339059327373f,-0.35355339059327373f, 0.35355339059327373f,
    0.35355339059327373f,-0.35355339059327373f,-0.35355339059327373f, 0.35355339059327373f },
  { 0.27778511650980114f,-0.49039264020161522f, 0.09754516100806412f, 0.41573480615127262f,
   -0.41573480615127262f,-0.09754516100806412f, 0.49039264020161522f,-0.27778511650980114f },
  { 0.19134171618254492f,-0.46193976625564337f, 0.46193976625564337f,-0.19134171618254492f,
   -0.19134171618254492f, 0.46193976625564337f,-0.46193976625564337f, 0.19134171618254492f },
  { 0.09754516100806412f,-0.27778511650980114f, 0.41573480615127262f,-0.49039264020161522f,
    0.49039264020161522f,-0.41573480615127262f, 0.27778511650980114f,-0.09754516100806412f }
};

// t_32 = a^32 * t0 - min * sum_{k=1..32} a^k, a = 1/(max-min+eps)
__global__ void precomp_norm(const float* __restrict__ max_,
                             const float* __restrict__ min_,
                             float* __restrict__ so) {
    int i = blockIdx.x * 256 + threadIdx.x;
    if (i >= NPAIR) return;
    float mn = min_[i], mx = max_[i];
    float d = mx - mn + EPS;
    float a = 1.0f / d;
    float a2 = a * a, a4 = a2 * a2, a8 = a4 * a4, a16 = a8 * a8, a32 = a16 * a16;
    float geo = a * (1.0f - a32) / (1.0f - a);   // sum_{k=1..32} a^k
    so[2 * i]     = a32;
    so[2 * i + 1] = -mn * geo;
}

template <bool USE_WS>
__global__ __launch_bounds__(384, 4)
void dct_kernel(const float* __restrict__ x,
                const float* __restrict__ ycbcr_w,
                const float* __restrict__ so,
                const float* __restrict__ max_,
                const float* __restrict__ min_,
                float* __restrict__ out) {
    // block = band (b*64+by); 6 waves = 3 channels x 2 column-halves.
    // Waves 0,1,2 = half 0 / c 0,1,2; waves 3,4,5 = half 1 / c 0,1,2.
    // The channel trio of a half issues identical load addresses on one
    // CU -> L1/MSHR dedup of the 3x re-read.
    const int wave = threadIdx.x >> 6;
    const int lane = threadIdx.x & 63;
    const int half = (wave >= 3) ? 1 : 0;
    const int c    = wave - half * 3;      // YCbCr channel
    const int rh   = lane >> 5;            // row-half: rows rh*4 .. rh*4+3
    const int lx   = lane & 31;            // block-col within the half

    const int band = blockIdx.x;
    const int by   = band & 63;
    const int b    = band >> 6;
    const int bx   = half * 32 + lx;       // this lane's 8x8 block column

    // channel weights (wave-uniform)
    const float wr = ycbcr_w[3 * c];
    const float wg = ycbcr_w[3 * c + 1];
    const float wb = ycbcr_w[3 * c + 2];

    // lane's 4 rows start here
    const float* base = x + (size_t)(b * 3) * CHST
                          + (size_t)(by * 8 + rh * 4) * HW + bx * 8;

    float acc[4][8];   // acc[u0][v] for u = rh*4 + u0
#pragma unroll
    for (int u0 = 0; u0 < 4; ++u0)
#pragma unroll
        for (int v = 0; v < 8; ++v) acc[u0][v] = 0.0f;

#pragma unroll
    for (int t = 0; t < 4; ++t) {
        const float* rp = base + t * HW;
        // lane bx reads 32B at bx*32 -> wave covers a contiguous 2KB row
        float4 r0 = *(const float4*)(rp);
        float4 r1 = *(const float4*)(rp + 4);
        float4 g0 = *(const float4*)(rp + CHST);
        float4 g1 = *(const float4*)(rp + CHST + 4);
        float4 b0 = *(const float4*)(rp + 2 * CHST);
        float4 b1 = *(const float4*)(rp + 2 * CHST + 4);

        float y[8];
        y[0] = fmaf(wr, r0.x, fmaf(wg, g0.x, wb * b0.x));
        y[1] = fmaf(wr, r0.y, fmaf(wg, g0.y, wb * b0.y));
        y[2] = fmaf(wr, r0.z, fmaf(wg, g0.z, wb * b0.z));
        y[3] = fmaf(wr, r0.w, fmaf(wg, g0.w, wb * b0.w));
        y[4] = fmaf(wr, r1.x, fmaf(wg, g1.x, wb * b1.x));
        y[5] = fmaf(wr, r1.y, fmaf(wg, g1.y, wb * b1.y));
        y[6] = fmaf(wr, r1.z, fmaf(wg, g1.z, wb * b1.z));
        y[7] = fmaf(wr, r1.w, fmaf(wg, g1.w, wb * b1.w));

        // row DCT: z[v] = sum_j basis[v][j] * y[j]
        float z[8];
#pragma unroll
        for (int v = 0; v < 8; ++v) {
            float zz = y[0] * BASIS[v][0];
#pragma unroll
            for (int j = 1; j < 8; ++j)
                zz = fmaf(y[j], BASIS[v][j], zz);
            z[v] = zz;
        }

        // partner row-half's z for the same block (lane ^ 32)
        float pz[8];
#pragma unroll
        for (int v = 0; v < 8; ++v)
            pz[v] = __shfl_xor(z[v], 32, 64);

        // column accumulate: own row gi = rh*4+t, partner row (1-rh)*4+t.
        // Compile-time indices, runtime rh -> v_cndmask between literals.
#pragma unroll
        for (int u0 = 0; u0 < 4; ++u0) {
            const float bo = rh ? BASIS[4 + u0][4 + t] : BASIS[u0][t];
            const float bp = rh ? BASIS[4 + u0][t]     : BASIS[u0][4 + t];
#pragma unroll
            for (int v = 0; v < 8; ++v)
                acc[u0][v] = fmaf(bo, z[v], fmaf(bp, pz[v], acc[u0][v]));
        }
    }

    const int obase = b * 192 + c * 64;    // first output channel index
    const int uh    = rh * 4;              // lane stores its u-half
    float* op = out + ((size_t)obase * 64 + by) * 64 + bx;
    const float2* sop = (const float2*)so + obase;   // (scale, offset) pairs

#pragma unroll
    for (int u0 = 0; u0 < 4; ++u0) {
#pragma unroll
        for (int v = 0; v < 8; ++v) {
            const int k = (uh + u0) * 8 + v;
            float s, o;
            if (USE_WS) {
                float2 p = sop[k];                 // L1-hit small table
                s = p.x;
                o = p.y;
            } else {
                float mn = min_[obase + k], mx = max_[obase + k];
                float d  = mx - mn + EPS;
                float a  = 1.0f / d;
                float a2 = a * a, a4 = a2 * a2, a8 = a4 * a4, a16 = a8 * a8, a32 = a16 * a16;
                s = a32;
                o = -mn * (a * (1.0f - a32) / (1.0f - a));
            }
            op[(size_t)k * 4096] = fmaf(s, acc[u0][v], o);
        }
    }
}

extern "C" void kernel_launch(void* const* d_in, const int* in_sizes, int n_in,
                              void* d_out, int out_size, void* d_ws, size_t ws_size,
                              hipStream_t stream) {
    const float* x    = (const float*)d_in[0];
    const float* max_ = (const float*)d_in[1];
    const float* min_ = (const float*)d_in[2];
    const float* yw   = (const float*)d_in[3];
    float* out = (float*)d_out;
    float* so  = (float*)d_ws;

    const bool use_ws = (ws_size >= (size_t)NPAIR * 2 * sizeof(float));
    // 2048 bands; one band per 384-thread block (6 waves).
    if (use_ws) {
        precomp_norm<<<(NPAIR + 255) / 256, 256, 0, stream>>>(max_, min_, so);
        dct_kernel<true><<<2048, 384, 0, stream>>>(x, yw, so, max_, min_, out);
    } else {
        dct_kernel<false><<<2048, 384, 0, stream>>>(x, yw, nullptr, max_, min_, out);
    }
}